// Round 6
// baseline (122.391 us; speedup 1.0000x reference)
//
#include <hip/hip_runtime.h>

typedef __bf16 bf16_t;
typedef __bf16 bf16x8 __attribute__((ext_vector_type(8)));
typedef float  f32x4  __attribute__((ext_vector_type(4)));

#define Ldim 2048
#define Ddim 256

#define USTRIDE 2064           // f32 per d-row of U_t (2048 + 8 pad + align)
#define UOFF    8              // pad rows: l_abs = idx - 8; rows 0..7 hold bias
#define U_WS_BYTE_OFF (1 << 20)

// Build frag-major (B-operand) bf16 copies of weight and input_weight.
// Frag element ((kt*16+nt)*64 + lane)*8 + j  =  W[k=kt*32+(lane>>4)*8+j][n=nt*16+(lane&15)]
// Blocks 0..7 additionally fill batch b's 8 U_t pad rows with bias (padded-window u == bias).
__global__ void swz_kernel(const float* __restrict__ w,
                           const float* __restrict__ win,
                           const float* __restrict__ bias,
                           bf16_t* __restrict__ wsw,
                           bf16_t* __restrict__ winsw,
                           float* __restrict__ Ut) {
    int blk = blockIdx.x;
    int mat = blk >> 3, kt = blk & 7;
    const float* src = mat ? win : w;
    bf16_t*      dst = mat ? winsw : wsw;
    int ln = threadIdx.x & 63, g = threadIdx.x >> 6;
    int c = ln & 15, q = ln >> 4;
#pragma unroll
    for (int i = 0; i < 4; ++i) {
        int nt = g + 4 * i;
        bf16x8 v;
#pragma unroll
        for (int j = 0; j < 8; ++j)
            v[j] = (bf16_t)src[(kt * 32 + q * 8 + j) * Ddim + nt * 16 + c];
        *(bf16x8*)&dst[((kt * 16 + nt) * 64 + ln) * 8] = v;
    }
    if (blk < 8) {
        // batch = blk; thread d = threadIdx.x fills pad rows 0..7 of U_t[d]
        float bv = bias[threadIdx.x];
        float* p = Ut + ((long)(blk << 8) + threadIdx.x) * USTRIDE;
#pragma unroll
        for (int i = 0; i < 8; ++i) p[i] = bv;
    }
}

// U = X @ W_in + bias over all rows, written TRANSPOSED: U_t[d][l].
// Pure register GEMM: no LDS, no barriers. 512 blocks x 4 waves; block = 32 rows.
// C-fragment is column-major (lane holds col d, rows 4q+r) -> aligned f32x4 store.
__global__ __launch_bounds__(256, 2)
void gemm_u_kernel(const float* __restrict__ x,
                   const float* __restrict__ bias,
                   const bf16x8* __restrict__ winsw,
                   float* __restrict__ Ut)
{
    const int tid = threadIdx.x;
    const int w   = tid >> 6;
    const int ln  = tid & 63;
    const int c   = ln & 15;
    const int q   = ln >> 4;
    const int tile = blockIdx.x;
    const int bb  = tile >> 6;
    const int l0  = (tile & 63) * 32;

    int ncol[4];
#pragma unroll
    for (int nl = 0; nl < 4; ++nl) ncol[nl] = (w * 4 + nl) * 16 + c;

    f32x4 au[2][4];
#pragma unroll
    for (int nl = 0; nl < 4; ++nl) {
        float bv = bias[ncol[nl]];
#pragma unroll
        for (int mt = 0; mt < 2; ++mt) {
            f32x4 t = {bv, bv, bv, bv};
            au[mt][nl] = t;
        }
    }

    const float* xb = x + (long)bb * (Ldim * Ddim);

    auto loadX = [&](f32x4 (&buf)[2][2], int kt) {
#pragma unroll
        for (int mt = 0; mt < 2; ++mt) {
            const f32x4* p = (const f32x4*)(xb + (long)(l0 + mt * 16 + c) * Ddim
                                            + kt * 32 + q * 8);
            buf[mt][0] = p[0];
            buf[mt][1] = p[1];
        }
    };
    auto loadW = [&](bf16x8 (&wb)[4], int kt) {
#pragma unroll
        for (int nl = 0; nl < 4; ++nl)
            wb[nl] = winsw[(kt * 16 + 4 * w + nl) * 64 + ln];
    };
    auto step1 = [&](const f32x4 (&buf)[2][2], const bf16x8 (&wb)[4]) {
        bf16x8 aF[2];
#pragma unroll
        for (int mt = 0; mt < 2; ++mt)
#pragma unroll
            for (int jj = 0; jj < 4; ++jj) {
                aF[mt][jj]     = (bf16_t)buf[mt][0][jj];
                aF[mt][jj + 4] = (bf16_t)buf[mt][1][jj];
            }
#pragma unroll
        for (int nl = 0; nl < 4; ++nl)
#pragma unroll
            for (int mt = 0; mt < 2; ++mt)
                au[mt][nl] = __builtin_amdgcn_mfma_f32_16x16x32_bf16(
                    aF[mt], wb[nl], au[mt][nl], 0, 0, 0);
    };

    {
        f32x4  x0[2][2], x1[2][2];
        bf16x8 w0[4], w1[4];
        loadX(x0, 0); loadW(w0, 0);
#pragma unroll 1
        for (int kk = 0; kk < 4; ++kk) {
            loadX(x1, 2 * kk + 1); loadW(w1, 2 * kk + 1);
            step1(x0, w0);
            if (kk < 3) { loadX(x0, 2 * kk + 2); loadW(w0, 2 * kk + 2); }
            step1(x1, w1);
        }
    }

    // transposed, 16B-aligned stores: U_t[d][l], rows 4q+r consecutive in l
#pragma unroll
    for (int mt = 0; mt < 2; ++mt)
#pragma unroll
        for (int nl = 0; nl < 4; ++nl)
            *(f32x4*)&Ut[((long)((bb << 8) + ncol[nl])) * USTRIDE
                         + UOFF + l0 + mt * 16 + 4 * q] = au[mt][nl];
}

// Recurrence-only kernel. h-init + per-step acc-init read U_t from global
// (L2-resident, prefetched one t-step ahead -> no barrier dependency, unlike
// the old LDS au path). LDS = 32 KB hbuf double-buffer only.
__global__ __launch_bounds__(256, 2)
void rnn_kernel(const float* __restrict__ tau,
                const bf16x8* __restrict__ wsw,
                const float* __restrict__ Ut,
                float* __restrict__ out)
{
    __shared__ char hb[32768];   // [2 buf][2 mt][8 kt][1024]

    const int tid = threadIdx.x;
    const int w   = tid >> 6;        // wave: owns n-cols [64w, 64w+64)
    const int ln  = tid & 63;
    const int c   = ln & 15;
    const int q   = ln >> 4;
    const int tile = blockIdx.x;             // 512 tiles of 32 rows
    const int bb  = tile >> 6;               // batch
    const int l0  = (tile & 63) * 32;        // first output row within batch

    int   ncol[4];
    float itau[4];
    long  ubase[4];   // U_t padded index of (d=ncol, l_abs=l0) for this lane
#pragma unroll
    for (int nl = 0; nl < 4; ++nl) {
        ncol[nl]  = (w * 4 + nl) * 16 + c;
        itau[nl]  = 1.0f / tau[ncol[nl]];
        ubase[nl] = ((long)((bb << 8) + ncol[nl])) * USTRIDE + UOFF + l0;
    }

    // W B-fragments, register resident (128 VGPRs)
    bf16x8 bfr[8][4];
#pragma unroll
    for (int kt = 0; kt < 8; ++kt)
#pragma unroll
        for (int nl = 0; nl < 4; ++nl)
            bfr[kt][nl] = wsw[(kt * 16 + 4 * w + nl) * 64 + ln];

    // h init (t=0): h_1 = itau * relu(u at absolute row l0 + m' - 7).
    // Scalar loads: the -7 breaks 16B alignment (this was R5's off-by-7 bug:
    // it read ubase + m', i.e. the t=7 input, as the t=0 input).
    f32x4 h[2][4];
#pragma unroll
    for (int mt = 0; mt < 2; ++mt)
#pragma unroll
        for (int nl = 0; nl < 4; ++nl)
#pragma unroll
            for (int r = 0; r < 4; ++r) {
                float u = Ut[ubase[nl] - 7 + mt * 16 + 4 * q + r];
                h[mt][nl][r] = itau[nl] * fmaxf(u, 0.0f);
            }

    // per-lane scatter byte offsets (t-invariant), bank-conflict-free perm
    int offn[4];
#pragma unroll
    for (int nl = 0; nl < 4; ++nl) {
        int kk = ncol[nl];
        offn[nl] = (kk >> 5) * 1024 + ((kk >> 3) & 3) * 64 + q * 16 + (kk & 7) * 2;
    }
    const int permln = (((ln & 3) << 4) | ((ln >> 4) << 2) | ((ln >> 2) & 3)) * 16;

    // initial scatter of h into buf 0
#pragma unroll
    for (int mt = 0; mt < 2; ++mt)
#pragma unroll
        for (int nl = 0; nl < 4; ++nl)
#pragma unroll
            for (int r = 0; r < 4; ++r)
                *(bf16_t*)(hb + mt * 8192 + r * 256 + offn[nl]) =
                    (bf16_t)h[mt][nl][r];

    // prefetch u for t = 1 (scalar dwords; latency hidden under scatter+barrier)
    float up[2][4][4];
#pragma unroll
    for (int mt = 0; mt < 2; ++mt)
#pragma unroll
        for (int nl = 0; nl < 4; ++nl)
#pragma unroll
            for (int r = 0; r < 4; ++r)
                up[mt][nl][r] = Ut[ubase[nl] - 7 + 1 + mt * 16 + 4 * q + r];

    __syncthreads();

    int cur = 0;
#pragma unroll 1
    for (int t = 1; t < 8; ++t) {
        char* pc = hb + cur * 16384;
        char* pn = hb + (cur ^ 1) * 16384;
#pragma unroll
        for (int mt = 0; mt < 2; ++mt) {
            f32x4 acc[4];
#pragma unroll
            for (int nl = 0; nl < 4; ++nl) {
                f32x4 a = {up[mt][nl][0], up[mt][nl][1], up[mt][nl][2], up[mt][nl][3]};
                acc[nl] = a;
            }
            // prefetch this mt's u for t+1; next use is one full step away
            if (t < 7) {
#pragma unroll
                for (int nl = 0; nl < 4; ++nl)
#pragma unroll
                    for (int r = 0; r < 4; ++r)
                        up[mt][nl][r] =
                            Ut[ubase[nl] - 7 + (t + 1) + mt * 16 + 4 * q + r];
            }
            __builtin_amdgcn_s_setprio(1);
#pragma unroll
            for (int kt = 0; kt < 8; ++kt) {
                bf16x8 aF = *(const bf16x8*)(pc + (mt * 8 + kt) * 1024 + permln);
#pragma unroll
                for (int nl = 0; nl < 4; ++nl)
                    acc[nl] = __builtin_amdgcn_mfma_f32_16x16x32_bf16(
                        aF, bfr[kt][nl], acc[nl], 0, 0, 0);
            }
            __builtin_amdgcn_s_setprio(0);
#pragma unroll
            for (int nl = 0; nl < 4; ++nl)
#pragma unroll
                for (int r = 0; r < 4; ++r) {
                    float hh = h[mt][nl][r];
                    float s  = fmaxf(acc[nl][r], 0.0f);
                    h[mt][nl][r] = hh + itau[nl] * (s - hh);
                }
            if (t < 7) {
#pragma unroll
                for (int nl = 0; nl < 4; ++nl)
#pragma unroll
                    for (int r = 0; r < 4; ++r)
                        *(bf16_t*)(pn + mt * 8192 + r * 256 + offn[nl]) =
                            (bf16_t)h[mt][nl][r];
            }
        }
        if (t < 7) __syncthreads();
        cur ^= 1;
    }

    // ------------- epilogue -------------
    float* ob = out + ((long)bb * Ldim + l0) * Ddim;
#pragma unroll
    for (int mt = 0; mt < 2; ++mt)
#pragma unroll
        for (int nl = 0; nl < 4; ++nl)
#pragma unroll
            for (int r = 0; r < 4; ++r)
                ob[(mt * 16 + 4 * q + r) * Ddim + ncol[nl]] = h[mt][nl][r];
}

extern "C" void kernel_launch(void* const* d_in, const int* in_sizes, int n_in,
                              void* d_out, int out_size, void* d_ws, size_t ws_size,
                              hipStream_t stream) {
    const float* x            = (const float*)d_in[0];
    const float* weight       = (const float*)d_in[1];
    const float* input_weight = (const float*)d_in[2];
    const float* bias         = (const float*)d_in[3];
    const float* tau          = (const float*)d_in[4];
    (void)in_sizes; (void)n_in; (void)out_size; (void)ws_size;

    bf16_t* wsw   = (bf16_t*)d_ws;
    bf16_t* winsw = wsw + 65536;
    float*  Ut    = (float*)((char*)d_ws + U_WS_BYTE_OFF);  // 8*256*2064*4 = 16.9 MB

    swz_kernel<<<16, 256, 0, stream>>>(weight, input_weight, bias, wsw, winsw, Ut);
    gemm_u_kernel<<<512, 256, 0, stream>>>(x, bias, (const bf16x8*)winsw, Ut);
    rnn_kernel<<<512, 256, 0, stream>>>(tau, (const bf16x8*)wsw, Ut, (float*)d_out);
}

// Round 7
// 115.479 us; speedup vs baseline: 1.0598x; 1.0598x over previous
//
#include <hip/hip_runtime.h>

typedef __bf16 bf16_t;
typedef __bf16 bf16x8 __attribute__((ext_vector_type(8)));
typedef float  f32x4  __attribute__((ext_vector_type(4)));

#define Ldim 2048
#define Ddim 256

// Build frag-major (B-operand) bf16 copies of weight and input_weight.
// Frag element ((kt*16+nt)*64 + lane)*8 + j  =  W[k=kt*32+(lane>>4)*8+j][n=nt*16+(lane&15)]
__global__ void swz_kernel(const float* __restrict__ w,
                           const float* __restrict__ win,
                           bf16_t* __restrict__ wsw,
                           bf16_t* __restrict__ winsw) {
    int mat = blockIdx.x >> 3, kt = blockIdx.x & 7;
    const float* src = mat ? win : w;
    bf16_t*      dst = mat ? winsw : wsw;
    int ln = threadIdx.x & 63, g = threadIdx.x >> 6;
    int c = ln & 15, q = ln >> 4;
#pragma unroll
    for (int i = 0; i < 4; ++i) {
        int nt = g + 4 * i;
        bf16x8 v;
#pragma unroll
        for (int j = 0; j < 8; ++j)
            v[j] = (bf16_t)src[(kt * 32 + q * 8 + j) * Ddim + nt * 16 + c];
        *(bf16x8*)&dst[((kt * 16 + nt) * 64 + ln) * 8] = v;
    }
}

#define AU_STRIDE 258   // f32; 4-row step = 1032 B -> 2-way bank alias (free)
#define AU_ROWS   72    // window rows 0..70 used (l0-7 .. l0+63)
#define AU_BYTES  (AU_ROWS * AU_STRIDE * 4)   // 74304
#define HBUF_BYTES 65536                      // [2 tile][2 buf][2 mt][8 kt][1024]
#define LDS_TOTAL (HBUF_BYTES + AU_BYTES)     // 139840 -> 1 block/CU

extern __shared__ char ldsmem[];

// Dual-tile interleaved recurrence: one 256-thr block owns TWO 32-row tiles
// (contiguous 64 rows). Per step the wave interleaves tile A's MFMA phase with
// tile B's load/update phases -> independent in-wave work fills every gather
// latency and post-MFMA VALU window (3 rounds showed co-resident WAVES can't
// do this: they stall on the same barrier in lockstep). 7 barriers total.
__global__ __launch_bounds__(256, 1)
void rnn_kernel(const float* __restrict__ x,
                const float* __restrict__ bias,
                const float* __restrict__ tau,
                const bf16x8* __restrict__ wsw,
                const bf16x8* __restrict__ winsw,
                float* __restrict__ out)
{
    char*  hbA = ldsmem;                 // tile A dbuf: +cur*16384
    char*  hbB = ldsmem + 32768;         // tile B dbuf
    float* auf = (float*)(ldsmem + HBUF_BYTES);

    const int tid = threadIdx.x;
    const int w   = tid >> 6;        // wave: owns n-cols [64w, 64w+64)
    const int ln  = tid & 63;
    const int c   = ln & 15;
    const int q   = ln >> 4;
    const int blk = blockIdx.x;
    const int bb  = blk >> 5;            // batch
    const int l0  = (blk & 31) * 64;     // first output row within batch

    int   ncol[4];
    float itau[4];
#pragma unroll
    for (int nl = 0; nl < 4; ++nl) {
        ncol[nl] = (w * 4 + nl) * 16 + c;
        itau[nl] = 1.0f / tau[ncol[nl]];
    }

    // ------------- phase 1: au = X_window @ W_in + bias (C layout) -------------
    // 5 mt tiles cover au rows 0..79 (abs rows l0-7 .. l0+72); rows 0..70 used.
    f32x4 au[5][4];
#pragma unroll
    for (int nl = 0; nl < 4; ++nl) {
        float bv = bias[ncol[nl]];
#pragma unroll
        for (int mt = 0; mt < 5; ++mt) {
            f32x4 t = {bv, bv, bv, bv};
            au[mt][nl] = t;
        }
    }

    const float* xb = x + (long)bb * (Ldim * Ddim);
    const f32x4 zf = {0.f, 0.f, 0.f, 0.f};

    auto loadX = [&](f32x4 (&buf)[5][2], int kt) {
#pragma unroll
        for (int mt = 0; mt < 5; ++mt) {
            int  lrow = l0 - 7 + mt * 16 + c;
            bool ok   = (lrow >= 0) && (lrow < Ldim);
            const f32x4* p = (const f32x4*)(xb + (long)lrow * Ddim + kt * 32 + q * 8);
            buf[mt][0] = ok ? p[0] : zf;
            buf[mt][1] = ok ? p[1] : zf;
        }
    };
    auto loadW = [&](bf16x8 (&wb)[4], int kt) {
#pragma unroll
        for (int nl = 0; nl < 4; ++nl)
            wb[nl] = winsw[(kt * 16 + 4 * w + nl) * 64 + ln];
    };
    auto step1 = [&](const f32x4 (&buf)[5][2], const bf16x8 (&wb)[4]) {
        bf16x8 aF[5];
#pragma unroll
        for (int mt = 0; mt < 5; ++mt)
#pragma unroll
            for (int jj = 0; jj < 4; ++jj) {
                aF[mt][jj]     = (bf16_t)buf[mt][0][jj];
                aF[mt][jj + 4] = (bf16_t)buf[mt][1][jj];
            }
#pragma unroll
        for (int nl = 0; nl < 4; ++nl)
#pragma unroll
            for (int mt = 0; mt < 5; ++mt)
                au[mt][nl] = __builtin_amdgcn_mfma_f32_16x16x32_bf16(
                    aF[mt], wb[nl], au[mt][nl], 0, 0, 0);
    };

    {
        f32x4  x0[5][2], x1[5][2];
        bf16x8 w0[4], w1[4];
        loadX(x0, 0); loadW(w0, 0);
#pragma unroll 1
        for (int kk = 0; kk < 4; ++kk) {
            loadX(x1, 2 * kk + 1); loadW(w1, 2 * kk + 1);
            step1(x0, w0);
            if (kk < 3) { loadX(x0, 2 * kk + 2); loadW(w0, 2 * kk + 2); }
            step1(x1, w1);
        }
    }

    // spill au -> LDS (rows 0..71; u-reads use rows <= 70)
#pragma unroll
    for (int mt = 0; mt < 5; ++mt)
#pragma unroll
        for (int nl = 0; nl < 4; ++nl)
#pragma unroll
            for (int r = 0; r < 4; ++r) {
                int row = mt * 16 + q * 4 + r;
                if (row < AU_ROWS)
                    auf[row * AU_STRIDE + ncol[nl]] = au[mt][nl][r];
            }

    // h init: h_1 = itau * relu(u at window row m), m = mt*16 + 4q + r (0..63)
    // mt 0,1 -> tile A; mt 2,3 -> tile B (direct from au regs, no shuffle)
    f32x4 h[4][4];
#pragma unroll
    for (int mt = 0; mt < 4; ++mt)
#pragma unroll
        for (int nl = 0; nl < 4; ++nl)
#pragma unroll
            for (int r = 0; r < 4; ++r)
                h[mt][nl][r] = itau[nl] * fmaxf(au[mt][nl][r], 0.0f);

    // W B-fragments, register resident (128 VGPRs), shared by both tiles
    bf16x8 bfr[8][4];
#pragma unroll
    for (int kt = 0; kt < 8; ++kt)
#pragma unroll
        for (int nl = 0; nl < 4; ++nl)
            bfr[kt][nl] = wsw[(kt * 16 + 4 * w + nl) * 64 + ln];

    // per-lane scatter byte offsets (t-invariant), bank-conflict-free perm
    int offn[4];
#pragma unroll
    for (int nl = 0; nl < 4; ++nl) {
        int kk = ncol[nl];
        offn[nl] = (kk >> 5) * 1024 + ((kk >> 3) & 3) * 64 + q * 16 + (kk & 7) * 2;
    }
    const int permln = (((ln & 3) << 4) | ((ln >> 4) << 2) | ((ln >> 2) & 3)) * 16;

    // initial scatter of h into buf 0 of each tile
#pragma unroll
    for (int mt = 0; mt < 2; ++mt)
#pragma unroll
        for (int nl = 0; nl < 4; ++nl)
#pragma unroll
            for (int r = 0; r < 4; ++r) {
                *(bf16_t*)(hbA + mt * 8192 + r * 256 + offn[nl]) =
                    (bf16_t)h[mt][nl][r];
                *(bf16_t*)(hbB + mt * 8192 + r * 256 + offn[nl]) =
                    (bf16_t)h[mt + 2][nl][r];
            }
    __syncthreads();

    int cur = 0;
#pragma unroll 1
    for (int t = 1; t < 8; ++t) {
        char* pAc = hbA + cur * 16384;
        char* pAn = hbA + (cur ^ 1) * 16384;
        char* pBc = hbB + cur * 16384;
        char* pBn = hbB + (cur ^ 1) * 16384;

        // ---- tile A: u loads + gathers + MFMA ----
        f32x4 accA[2][4];
#pragma unroll
        for (int mt = 0; mt < 2; ++mt)
#pragma unroll
            for (int nl = 0; nl < 4; ++nl)
#pragma unroll
                for (int r = 0; r < 4; ++r)
                    accA[mt][nl][r] =
                        auf[(mt * 16 + 4 * q + r + t) * AU_STRIDE + ncol[nl]];
        bf16x8 aFA[2][8];
#pragma unroll
        for (int mt = 0; mt < 2; ++mt)
#pragma unroll
            for (int kt = 0; kt < 8; ++kt)
                aFA[mt][kt] = *(const bf16x8*)(pAc + (mt * 8 + kt) * 1024 + permln);
#pragma unroll
        for (int mt = 0; mt < 2; ++mt)
#pragma unroll
            for (int kt = 0; kt < 8; ++kt)
#pragma unroll
                for (int nl = 0; nl < 4; ++nl)
                    accA[mt][nl] = __builtin_amdgcn_mfma_f32_16x16x32_bf16(
                        aFA[mt][kt], bfr[kt][nl], accA[mt][nl], 0, 0, 0);

        // ---- tile B: issue u loads + gathers (fly under A's update + MFMA B) ----
        f32x4 accB[2][4];
#pragma unroll
        for (int mt = 0; mt < 2; ++mt)
#pragma unroll
            for (int nl = 0; nl < 4; ++nl)
#pragma unroll
                for (int r = 0; r < 4; ++r)
                    accB[mt][nl][r] =
                        auf[(32 + mt * 16 + 4 * q + r + t) * AU_STRIDE + ncol[nl]];
        bf16x8 aFB[2][8];
#pragma unroll
        for (int mt = 0; mt < 2; ++mt)
#pragma unroll
            for (int kt = 0; kt < 8; ++kt)
                aFB[mt][kt] = *(const bf16x8*)(pBc + (mt * 8 + kt) * 1024 + permln);

        // ---- update + scatter A (VALU/ds_write, overlaps MFMA B issue) ----
#pragma unroll
        for (int mt = 0; mt < 2; ++mt)
#pragma unroll
            for (int nl = 0; nl < 4; ++nl)
#pragma unroll
                for (int r = 0; r < 4; ++r) {
                    float hh = h[mt][nl][r];
                    float s  = fmaxf(accA[mt][nl][r], 0.0f);
                    hh = hh + itau[nl] * (s - hh);
                    h[mt][nl][r] = hh;
                    if (t < 7)
                        *(bf16_t*)(pAn + mt * 8192 + r * 256 + offn[nl]) = (bf16_t)hh;
                }

        // ---- MFMA B ----
#pragma unroll
        for (int mt = 0; mt < 2; ++mt)
#pragma unroll
            for (int kt = 0; kt < 8; ++kt)
#pragma unroll
                for (int nl = 0; nl < 4; ++nl)
                    accB[mt][nl] = __builtin_amdgcn_mfma_f32_16x16x32_bf16(
                        aFB[mt][kt], bfr[kt][nl], accB[mt][nl], 0, 0, 0);

        // ---- update + scatter B ----
#pragma unroll
        for (int mt = 0; mt < 2; ++mt)
#pragma unroll
            for (int nl = 0; nl < 4; ++nl)
#pragma unroll
                for (int r = 0; r < 4; ++r) {
                    float hh = h[mt + 2][nl][r];
                    float s  = fmaxf(accB[mt][nl][r], 0.0f);
                    hh = hh + itau[nl] * (s - hh);
                    h[mt + 2][nl][r] = hh;
                    if (t < 7)
                        *(bf16_t*)(pBn + mt * 8192 + r * 256 + offn[nl]) = (bf16_t)hh;
                }

        if (t < 7) __syncthreads();
        cur ^= 1;
    }

    // ------------- epilogue: 64 rows -------------
    float* ob = out + ((long)bb * Ldim + l0) * Ddim;
#pragma unroll
    for (int mt = 0; mt < 4; ++mt)
#pragma unroll
        for (int nl = 0; nl < 4; ++nl)
#pragma unroll
            for (int r = 0; r < 4; ++r)
                ob[(mt * 16 + 4 * q + r) * Ddim + ncol[nl]] = h[mt][nl][r];
}

extern "C" void kernel_launch(void* const* d_in, const int* in_sizes, int n_in,
                              void* d_out, int out_size, void* d_ws, size_t ws_size,
                              hipStream_t stream) {
    const float* x            = (const float*)d_in[0];
    const float* weight       = (const float*)d_in[1];
    const float* input_weight = (const float*)d_in[2];
    const float* bias         = (const float*)d_in[3];
    const float* tau          = (const float*)d_in[4];
    (void)in_sizes; (void)n_in; (void)out_size; (void)ws_size;

    bf16_t* wsw   = (bf16_t*)d_ws;
    bf16_t* winsw = wsw + 65536;

    static bool attr_set = false;
    if (!attr_set) {
        (void)hipFuncSetAttribute((const void*)rnn_kernel,
                                  hipFuncAttributeMaxDynamicSharedMemorySize,
                                  LDS_TOTAL);
        attr_set = true;
    }

    swz_kernel<<<16, 256, 0, stream>>>(weight, input_weight, wsw, winsw);
    rnn_kernel<<<256, 256, LDS_TOTAL, stream>>>(x, bias, tau,
                                                (const bf16x8*)wsw,
                                                (const bf16x8*)winsw,
                                                (float*)d_out);
}

// Round 8
// 108.020 us; speedup vs baseline: 1.1330x; 1.0691x over previous
//
#include <hip/hip_runtime.h>

typedef __bf16 bf16_t;
typedef __bf16 bf16x8 __attribute__((ext_vector_type(8)));
typedef float  f32x4  __attribute__((ext_vector_type(4)));

#define Ldim 2048
#define Ddim 256

// Build frag-major (B-operand) bf16 copies of weight and input_weight.
// Frag element ((kt*16+nt)*64 + lane)*8 + j  =  W[k=kt*32+(lane>>4)*8+j][n=nt*16+(lane&15)]
__global__ void swz_kernel(const float* __restrict__ w,
                           const float* __restrict__ win,
                           bf16_t* __restrict__ wsw,
                           bf16_t* __restrict__ winsw) {
    int mat = blockIdx.x >> 3, kt = blockIdx.x & 7;
    const float* src = mat ? win : w;
    bf16_t*      dst = mat ? winsw : wsw;
    int ln = threadIdx.x & 63, g = threadIdx.x >> 6;
    int c = ln & 15, q = ln >> 4;
#pragma unroll
    for (int i = 0; i < 4; ++i) {
        int nt = g + 4 * i;
        bf16x8 v;
#pragma unroll
        for (int j = 0; j < 8; ++j)
            v[j] = (bf16_t)src[(kt * 32 + q * 8 + j) * Ddim + nt * 16 + c];
        *(bf16x8*)&dst[((kt * 16 + nt) * 64 + ln) * 8] = v;
    }
}

#define AU_STRIDE 258   // f32; 4-row step = 1032 B -> 2-way bank alias (free)
#define AU_ROWS   40
#define AU_BYTES  (AU_ROWS * AU_STRIDE * 4)       // 41280
#define HBUF_BYTES 32768                          // [2 buf][2 mt][8 kt][1024]
#define LDS_TOTAL (HBUF_BYTES + AU_BYTES)         // 74048 -> 2 blocks/CU

extern __shared__ char ldsmem[];

// R4 shape (proven best): 256 thr = 4 waves, nl=4, 32-row tile, grid 512 =
// 2 independent blocks/CU. R8 changes: (1) per-step u values prefetched from
// LDS into registers ONE STEP EARLY (auf is static post-phase-1 and each wave
// reads only columns its own lanes wrote -> no barrier dependency; latency
// hides under prior step's MFMA/update/barrier); (2) all per-step LDS
// addressing via t-invariant base pointers + compile-time immediate offsets
// (kills ~190 VALU/step of address arithmetic on the critical chain).
__global__ __launch_bounds__(256, 2)
void rnn_kernel(const float* __restrict__ x,
                const float* __restrict__ bias,
                const float* __restrict__ tau,
                const bf16x8* __restrict__ wsw,
                const bf16x8* __restrict__ winsw,
                float* __restrict__ out)
{
    char*  hb  = ldsmem;                       // h A-frag double buffer
    float* auf = (float*)(ldsmem + HBUF_BYTES);

    const int tid = threadIdx.x;
    const int w   = tid >> 6;        // wave: owns n-cols [64w, 64w+64)
    const int ln  = tid & 63;
    const int c   = ln & 15;
    const int q   = ln >> 4;
    const int tile = blockIdx.x;             // 512 tiles of 32 rows
    const int bb  = tile >> 6;               // batch
    const int l0  = (tile & 63) * 32;        // first output row within batch

    int   ncol[4];
    float itau[4];
#pragma unroll
    for (int nl = 0; nl < 4; ++nl) {
        ncol[nl] = (w * 4 + nl) * 16 + c;
        itau[nl] = 1.0f / tau[ncol[nl]];
    }

    // ------------- phase 1: au = X_window @ W_in + bias (C layout) -------------
    // rows covered: l0-7 + [0,48)  (39 used: window rows 0..38)
    f32x4 au[3][4];
#pragma unroll
    for (int nl = 0; nl < 4; ++nl) {
        float bv = bias[ncol[nl]];
#pragma unroll
        for (int mt = 0; mt < 3; ++mt) {
            f32x4 t = {bv, bv, bv, bv};
            au[mt][nl] = t;
        }
    }

    const float* xb = x + (long)bb * (Ldim * Ddim);
    const f32x4 zf = {0.f, 0.f, 0.f, 0.f};

    auto loadX = [&](f32x4 (&buf)[3][2], int kt) {
#pragma unroll
        for (int mt = 0; mt < 3; ++mt) {
            int  lrow = l0 - 7 + mt * 16 + c;
            bool ok   = (lrow >= 0) && (lrow < Ldim);
            const f32x4* p = (const f32x4*)(xb + (long)lrow * Ddim + kt * 32 + q * 8);
            buf[mt][0] = ok ? p[0] : zf;
            buf[mt][1] = ok ? p[1] : zf;
        }
    };
    auto loadW = [&](bf16x8 (&wb)[4], int kt) {
#pragma unroll
        for (int nl = 0; nl < 4; ++nl)
            wb[nl] = winsw[(kt * 16 + 4 * w + nl) * 64 + ln];
    };
    auto step1 = [&](const f32x4 (&buf)[3][2], const bf16x8 (&wb)[4]) {
        bf16x8 aF[3];
#pragma unroll
        for (int mt = 0; mt < 3; ++mt)
#pragma unroll
            for (int jj = 0; jj < 4; ++jj) {
                aF[mt][jj]     = (bf16_t)buf[mt][0][jj];
                aF[mt][jj + 4] = (bf16_t)buf[mt][1][jj];
            }
#pragma unroll
        for (int nl = 0; nl < 4; ++nl)
#pragma unroll
            for (int mt = 0; mt < 3; ++mt)
                au[mt][nl] = __builtin_amdgcn_mfma_f32_16x16x32_bf16(
                    aF[mt], wb[nl], au[mt][nl], 0, 0, 0);
    };

    {
        f32x4  x0[3][2], x1[3][2];
        bf16x8 w0[4], w1[4];
        loadX(x0, 0); loadW(w0, 0);
#pragma unroll 1
        for (int kk = 0; kk < 4; ++kk) {
            loadX(x1, 2 * kk + 1); loadW(w1, 2 * kk + 1);
            step1(x0, w0);
            if (kk < 3) { loadX(x0, 2 * kk + 2); loadW(w0, 2 * kk + 2); }
            step1(x1, w1);
        }
    }

    // spill au -> LDS (wave-private column stripe; rows 0..38 used)
#pragma unroll
    for (int mt = 0; mt < 3; ++mt)
#pragma unroll
        for (int nl = 0; nl < 4; ++nl)
#pragma unroll
            for (int r = 0; r < 4; ++r) {
                int row = mt * 16 + q * 4 + r;
                if (row < 39)
                    auf[row * AU_STRIDE + ncol[nl]] = au[mt][nl][r];
            }

    // h init: h_1 = itau * relu(u at window row m), m = mt*16 + q*4 + r (0..31)
    f32x4 h[2][4];
#pragma unroll
    for (int mt = 0; mt < 2; ++mt)
#pragma unroll
        for (int nl = 0; nl < 4; ++nl)
#pragma unroll
            for (int r = 0; r < 4; ++r)
                h[mt][nl][r] = itau[nl] * fmaxf(au[mt][nl][r], 0.0f);

    // ------------- phase 2: 7 more recurrence steps -------------
    bf16x8 bfr[8][4];   // W B-fragments, register resident (128 VGPRs)
#pragma unroll
    for (int kt = 0; kt < 8; ++kt)
#pragma unroll
        for (int nl = 0; nl < 4; ++nl)
            bfr[kt][nl] = wsw[(kt * 16 + 4 * w + nl) * 64 + ln];

    // per-lane scatter byte offsets (t-invariant), bank-conflict-free perm
    int offn[4];
#pragma unroll
    for (int nl = 0; nl < 4; ++nl) {
        int kk = ncol[nl];
        offn[nl] = (kk >> 5) * 1024 + ((kk >> 3) & 3) * 64 + q * 16 + (kk & 7) * 2;
    }
    const int permln = (((ln & 3) << 4) | ((ln >> 4) << 2) | ((ln >> 2) & 3)) * 16;

    // initial scatter of h into buf 0
#pragma unroll
    for (int mt = 0; mt < 2; ++mt)
#pragma unroll
        for (int nl = 0; nl < 4; ++nl)
#pragma unroll
            for (int r = 0; r < 4; ++r)
                *(bf16_t*)(hb + mt * 8192 + r * 256 + offn[nl]) =
                    (bf16_t)h[mt][nl][r];

    // t-invariant u-read base pointers (bumped += AU_STRIDE per step);
    // reads use compile-time immediates (mt*16+r)*AU_STRIDE*4 <= 19.6 KB.
    const float* ub[4];
#pragma unroll
    for (int nl = 0; nl < 4; ++nl)
        ub[nl] = auf + (4 * q + 1) * AU_STRIDE + ncol[nl];

    // prefetch u for t=1 into registers (wave-self-contained: this wave's
    // lanes wrote these rows/cols of auf -> no barrier needed, lgkm orders)
    float up[2][4][4];
#pragma unroll
    for (int mt = 0; mt < 2; ++mt)
#pragma unroll
        for (int nl = 0; nl < 4; ++nl)
#pragma unroll
            for (int r = 0; r < 4; ++r)
                up[mt][nl][r] = ub[nl][(mt * 16 + r) * AU_STRIDE];

    __syncthreads();

    int cur = 0;
#pragma unroll 1
    for (int t = 1; t < 8; ++t) {
        char* pc = hb + cur * 16384 + permln;   // gather base (+imm)
        char* pn = hb + (cur ^ 1) * 16384;      // scatter base (+offn+imm)
#pragma unroll
        for (int mt = 0; mt < 2; ++mt) {
            f32x4 acc[4];
#pragma unroll
            for (int nl = 0; nl < 4; ++nl) {
                f32x4 a = {up[mt][nl][0], up[mt][nl][1], up[mt][nl][2], up[mt][nl][3]};
                acc[nl] = a;
            }
            // after mt1's up consumed: bump bases and prefetch next step's u
            if (mt == 1 && t < 7) {
#pragma unroll
                for (int nl = 0; nl < 4; ++nl) ub[nl] += AU_STRIDE;
#pragma unroll
                for (int m2 = 0; m2 < 2; ++m2)
#pragma unroll
                    for (int nl = 0; nl < 4; ++nl)
#pragma unroll
                        for (int r = 0; r < 4; ++r)
                            up[m2][nl][r] = ub[nl][(m2 * 16 + r) * AU_STRIDE];
            }
            __builtin_amdgcn_s_setprio(1);
#pragma unroll
            for (int kt = 0; kt < 8; ++kt) {
                bf16x8 aF = *(const bf16x8*)(pc + (mt * 8 + kt) * 1024);
#pragma unroll
                for (int nl = 0; nl < 4; ++nl)
                    acc[nl] = __builtin_amdgcn_mfma_f32_16x16x32_bf16(
                        aF, bfr[kt][nl], acc[nl], 0, 0, 0);
            }
            __builtin_amdgcn_s_setprio(0);
#pragma unroll
            for (int nl = 0; nl < 4; ++nl)
#pragma unroll
                for (int r = 0; r < 4; ++r) {
                    float hh = h[mt][nl][r];
                    float s  = fmaxf(acc[nl][r], 0.0f);
                    hh = hh + itau[nl] * (s - hh);
                    h[mt][nl][r] = hh;
                    if (t < 7)
                        *(bf16_t*)(pn + mt * 8192 + r * 256 + offn[nl]) = (bf16_t)hh;
                }
        }
        if (t < 7) __syncthreads();
        cur ^= 1;
    }

    // ------------- epilogue -------------
    float* ob = out + ((long)bb * Ldim + l0) * Ddim;
#pragma unroll
    for (int mt = 0; mt < 2; ++mt)
#pragma unroll
        for (int nl = 0; nl < 4; ++nl)
#pragma unroll
            for (int r = 0; r < 4; ++r)
                ob[(mt * 16 + 4 * q + r) * Ddim + ncol[nl]] = h[mt][nl][r];
}

extern "C" void kernel_launch(void* const* d_in, const int* in_sizes, int n_in,
                              void* d_out, int out_size, void* d_ws, size_t ws_size,
                              hipStream_t stream) {
    const float* x            = (const float*)d_in[0];
    const float* weight       = (const float*)d_in[1];
    const float* input_weight = (const float*)d_in[2];
    const float* bias         = (const float*)d_in[3];
    const float* tau          = (const float*)d_in[4];
    (void)in_sizes; (void)n_in; (void)out_size; (void)ws_size;

    bf16_t* wsw   = (bf16_t*)d_ws;
    bf16_t* winsw = wsw + 65536;

    static bool attr_set = false;
    if (!attr_set) {
        (void)hipFuncSetAttribute((const void*)rnn_kernel,
                                  hipFuncAttributeMaxDynamicSharedMemorySize,
                                  LDS_TOTAL);
        attr_set = true;
    }

    swz_kernel<<<16, 256, 0, stream>>>(weight, input_weight, wsw, winsw);
    rnn_kernel<<<512, 256, LDS_TOTAL, stream>>>(x, bias, tau,
                                                (const bf16x8*)wsw,
                                                (const bf16x8*)winsw,
                                                (float*)d_out);
}

// Round 9
// 104.614 us; speedup vs baseline: 1.1699x; 1.0326x over previous
//
#include <hip/hip_runtime.h>

typedef __bf16 bf16_t;
typedef __bf16 bf16x8 __attribute__((ext_vector_type(8)));
typedef float  f32x4  __attribute__((ext_vector_type(4)));

#define Ldim 2048
#define Ddim 256

// Build frag-major (B-operand) bf16 copies of weight and input_weight.
// Frag element ((kt*16+nt)*64 + lane)*8 + j  =  W[k=kt*32+(lane>>4)*8+j][n=nt*16+(lane&15)]
__global__ void swz_kernel(const float* __restrict__ w,
                           const float* __restrict__ win,
                           bf16_t* __restrict__ wsw,
                           bf16_t* __restrict__ winsw) {
    int mat = blockIdx.x >> 3, kt = blockIdx.x & 7;
    const float* src = mat ? win : w;
    bf16_t*      dst = mat ? winsw : wsw;
    int ln = threadIdx.x & 63, g = threadIdx.x >> 6;
    int c = ln & 15, q = ln >> 4;
#pragma unroll
    for (int i = 0; i < 4; ++i) {
        int nt = g + 4 * i;
        bf16x8 v;
#pragma unroll
        for (int j = 0; j < 8; ++j)
            v[j] = (bf16_t)src[(kt * 32 + q * 8 + j) * Ddim + nt * 16 + c];
        *(bf16x8*)&dst[((kt * 16 + nt) * 64 + ln) * 8] = v;
    }
}

#define AU_STRIDE 258   // f32; 4-row step = 1032 B -> 2-way bank alias (free)
#define AU_ROWS   40
#define AU_BYTES  (AU_ROWS * AU_STRIDE * 4)       // 41280
#define HBUF_BYTES 32768                          // [2 buf][2 mt][8 kt][1024]
#define XS_BYTES   32768                          // 32 chunk-halves x 1024 B (aliases auf)
#define LDS_TOTAL (HBUF_BYTES + AU_BYTES)         // 74048 -> 2 blocks/CU

extern __shared__ char ldsmem[];

// R8 base + cooperative X staging: the block's mt=0,1 X rows (32 KB) are
// loaded ONCE (8 f32x4/wave, all 4 waves) and ds_written into chunk layout
// [mt*16+kt*2+h][lane*16] so phase-1's read-back is identity-per-lane (dense,
// conflict-free b128, zero global loads for mt 0,1). One exposed HBM latency
// per block instead of 8 partially-hidden ones. xstage aliases auf (dead
// after phase-1 / born after; barrier between). mt=2 tail keeps the depth-2
// global pipeline. Everything else identical to R8.
__global__ __launch_bounds__(256, 2)
void rnn_kernel(const float* __restrict__ x,
                const float* __restrict__ bias,
                const float* __restrict__ tau,
                const bf16x8* __restrict__ wsw,
                const bf16x8* __restrict__ winsw,
                float* __restrict__ out)
{
    char*  hb  = ldsmem;                       // h A-frag double buffer
    char*  xs  = ldsmem + HBUF_BYTES;          // X stage (aliases auf)
    float* auf = (float*)(ldsmem + HBUF_BYTES);

    const int tid = threadIdx.x;
    const int w   = tid >> 6;        // wave: owns n-cols [64w, 64w+64)
    const int ln  = tid & 63;
    const int c   = ln & 15;
    const int q   = ln >> 4;
    const int tile = blockIdx.x;             // 512 tiles of 32 rows
    const int bb  = tile >> 6;               // batch
    const int l0  = (tile & 63) * 32;        // first output row within batch

    int   ncol[4];
    float itau[4];
#pragma unroll
    for (int nl = 0; nl < 4; ++nl) {
        ncol[nl] = (w * 4 + nl) * 16 + c;
        itau[nl] = 1.0f / tau[ncol[nl]];
    }

    const float* xb = x + (long)bb * (Ldim * Ddim);
    const f32x4 zf = {0.f, 0.f, 0.f, 0.f};

    // ---- cooperative X stage: chunk-half flat = mt*16 + kt*2 + h (mt in {0,1}) ----
    // lane ln of chunk (mt,kt,h) holds x[l0-7+mt*16+(ln&15)][kt*32+(ln>>4)*8+h*4 ..+4]
    f32x4 sv[8];
    int   sfl[8];
#pragma unroll
    for (int it = 0; it < 8; ++it) {
        int flat = it * 4 + w;
        sfl[it] = flat;
        int mt = flat >> 4, kt = (flat >> 1) & 7, hh = flat & 1;
        int lrow = l0 - 7 + mt * 16 + c;               // <= l0+24, >= -7
        int rcl  = lrow < 0 ? 0 : lrow;
        const f32x4* g = (const f32x4*)(xb + (long)rcl * Ddim + kt * 32 + q * 8 + hh * 4);
        f32x4 v = *g;
        sv[it] = (lrow >= 0) ? v : zf;
    }

    // phase-1 weight dbuf: issue first two kt AFTER sv loads (counted vmcnt lets
    // the ds_writes below wait only on sv, with winsw still in flight)
    bf16x8 w0[4], w1[4];
    auto loadW = [&](bf16x8 (&wb)[4], int kt) {
#pragma unroll
        for (int nl = 0; nl < 4; ++nl)
            wb[nl] = winsw[(kt * 16 + 4 * w + nl) * 64 + ln];
    };
    loadW(w0, 0); loadW(w1, 1);

#pragma unroll
    for (int it = 0; it < 8; ++it)
        *(f32x4*)(xs + sfl[it] * 1024 + ln * 16) = sv[it];

    // ------------- phase 1: au = X_window @ W_in + bias (C layout) -------------
    f32x4 au[3][4];
#pragma unroll
    for (int nl = 0; nl < 4; ++nl) {
        float bv = bias[ncol[nl]];
#pragma unroll
        for (int mt = 0; mt < 3; ++mt) {
            f32x4 t = {bv, bv, bv, bv};
            au[mt][nl] = t;
        }
    }

    // mt=2 tail rows (l0+25+c), depth-2 global pipeline
    auto loadXg = [&](f32x4 (&buf)[2], int kt) {
        int  lrow = l0 + 25 + c;
        bool ok   = lrow < Ldim;
        const f32x4* p = (const f32x4*)(xb + (long)lrow * Ddim + kt * 32 + q * 8);
        buf[0] = ok ? p[0] : zf;
        buf[1] = ok ? p[1] : zf;
    };
    auto step1 = [&](int kt, const f32x4 (&xg)[2], const bf16x8 (&wb)[4]) {
        bf16x8 aF[3];
#pragma unroll
        for (int mt = 0; mt < 2; ++mt) {
            f32x4 b0 = *(const f32x4*)(xs + (mt * 16 + kt * 2 + 0) * 1024 + ln * 16);
            f32x4 b1 = *(const f32x4*)(xs + (mt * 16 + kt * 2 + 1) * 1024 + ln * 16);
#pragma unroll
            for (int jj = 0; jj < 4; ++jj) {
                aF[mt][jj]     = (bf16_t)b0[jj];
                aF[mt][jj + 4] = (bf16_t)b1[jj];
            }
        }
#pragma unroll
        for (int jj = 0; jj < 4; ++jj) {
            aF[2][jj]     = (bf16_t)xg[0][jj];
            aF[2][jj + 4] = (bf16_t)xg[1][jj];
        }
#pragma unroll
        for (int nl = 0; nl < 4; ++nl)
#pragma unroll
            for (int mt = 0; mt < 3; ++mt)
                au[mt][nl] = __builtin_amdgcn_mfma_f32_16x16x32_bf16(
                    aF[mt], wb[nl], au[mt][nl], 0, 0, 0);
    };

    {
        f32x4 xg0[2], xg1[2];
        loadXg(xg0, 0);
        __syncthreads();   // staged X visible to all waves
        loadXg(xg1, 1);
#pragma unroll 1
        for (int kk = 0; kk < 4; ++kk) {
            step1(2 * kk, xg0, w0);
            if (kk < 3) { loadXg(xg0, 2 * kk + 2); loadW(w0, 2 * kk + 2); }
            step1(2 * kk + 1, xg1, w1);
            if (kk < 3) { loadXg(xg1, 2 * kk + 3); loadW(w1, 2 * kk + 3); }
        }
    }

    __syncthreads();   // all waves done reading xs before auf overwrites it

    // spill au -> LDS (wave-private column stripe; rows 0..38 used)
#pragma unroll
    for (int mt = 0; mt < 3; ++mt)
#pragma unroll
        for (int nl = 0; nl < 4; ++nl)
#pragma unroll
            for (int r = 0; r < 4; ++r) {
                int row = mt * 16 + q * 4 + r;
                if (row < 39)
                    auf[row * AU_STRIDE + ncol[nl]] = au[mt][nl][r];
            }

    // h init: h_1 = itau * relu(u at window row m), m = mt*16 + q*4 + r (0..31)
    f32x4 h[2][4];
#pragma unroll
    for (int mt = 0; mt < 2; ++mt)
#pragma unroll
        for (int nl = 0; nl < 4; ++nl)
#pragma unroll
            for (int r = 0; r < 4; ++r)
                h[mt][nl][r] = itau[nl] * fmaxf(au[mt][nl][r], 0.0f);

    // ------------- phase 2: 7 more recurrence steps -------------
    bf16x8 bfr[8][4];   // W B-fragments, register resident (128 VGPRs)
#pragma unroll
    for (int kt = 0; kt < 8; ++kt)
#pragma unroll
        for (int nl = 0; nl < 4; ++nl)
            bfr[kt][nl] = wsw[(kt * 16 + 4 * w + nl) * 64 + ln];

    // per-lane scatter byte offsets (t-invariant), bank-conflict-free perm
    int offn[4];
#pragma unroll
    for (int nl = 0; nl < 4; ++nl) {
        int kk = ncol[nl];
        offn[nl] = (kk >> 5) * 1024 + ((kk >> 3) & 3) * 64 + q * 16 + (kk & 7) * 2;
    }
    const int permln = (((ln & 3) << 4) | ((ln >> 4) << 2) | ((ln >> 2) & 3)) * 16;

    // initial scatter of h into buf 0
#pragma unroll
    for (int mt = 0; mt < 2; ++mt)
#pragma unroll
        for (int nl = 0; nl < 4; ++nl)
#pragma unroll
            for (int r = 0; r < 4; ++r)
                *(bf16_t*)(hb + mt * 8192 + r * 256 + offn[nl]) =
                    (bf16_t)h[mt][nl][r];

    // t-invariant u-read base pointers (bumped += AU_STRIDE per step)
    const float* ub[4];
#pragma unroll
    for (int nl = 0; nl < 4; ++nl)
        ub[nl] = auf + (4 * q + 1) * AU_STRIDE + ncol[nl];

    // prefetch u for t=1 (wave-self-contained: this wave's lanes wrote these
    // rows/cols of auf -> no barrier needed, lgkm orders)
    float up[2][4][4];
#pragma unroll
    for (int mt = 0; mt < 2; ++mt)
#pragma unroll
        for (int nl = 0; nl < 4; ++nl)
#pragma unroll
            for (int r = 0; r < 4; ++r)
                up[mt][nl][r] = ub[nl][(mt * 16 + r) * AU_STRIDE];

    __syncthreads();

    int cur = 0;
#pragma unroll 1
    for (int t = 1; t < 8; ++t) {
        char* pc = hb + cur * 16384 + permln;   // gather base (+imm)
        char* pn = hb + (cur ^ 1) * 16384;      // scatter base (+offn+imm)
#pragma unroll
        for (int mt = 0; mt < 2; ++mt) {
            f32x4 acc[4];
#pragma unroll
            for (int nl = 0; nl < 4; ++nl) {
                f32x4 a = {up[mt][nl][0], up[mt][nl][1], up[mt][nl][2], up[mt][nl][3]};
                acc[nl] = a;
            }
            // after mt1's up consumed: bump bases and prefetch next step's u
            if (mt == 1 && t < 7) {
#pragma unroll
                for (int nl = 0; nl < 4; ++nl) ub[nl] += AU_STRIDE;
#pragma unroll
                for (int m2 = 0; m2 < 2; ++m2)
#pragma unroll
                    for (int nl = 0; nl < 4; ++nl)
#pragma unroll
                        for (int r = 0; r < 4; ++r)
                            up[m2][nl][r] = ub[nl][(m2 * 16 + r) * AU_STRIDE];
            }
            __builtin_amdgcn_s_setprio(1);
#pragma unroll
            for (int kt = 0; kt < 8; ++kt) {
                bf16x8 aF = *(const bf16x8*)(pc + (mt * 8 + kt) * 1024);
#pragma unroll
                for (int nl = 0; nl < 4; ++nl)
                    acc[nl] = __builtin_amdgcn_mfma_f32_16x16x32_bf16(
                        aF, bfr[kt][nl], acc[nl], 0, 0, 0);
            }
            __builtin_amdgcn_s_setprio(0);
#pragma unroll
            for (int nl = 0; nl < 4; ++nl)
#pragma unroll
                for (int r = 0; r < 4; ++r) {
                    float hh = h[mt][nl][r];
                    float s  = fmaxf(acc[nl][r], 0.0f);
                    hh = hh + itau[nl] * (s - hh);
                    h[mt][nl][r] = hh;
                    if (t < 7)
                        *(bf16_t*)(pn + mt * 8192 + r * 256 + offn[nl]) = (bf16_t)hh;
                }
        }
        if (t < 7) __syncthreads();
        cur ^= 1;
    }

    // ------------- epilogue -------------
    float* ob = out + ((long)bb * Ldim + l0) * Ddim;
#pragma unroll
    for (int mt = 0; mt < 2; ++mt)
#pragma unroll
        for (int nl = 0; nl < 4; ++nl)
#pragma unroll
            for (int r = 0; r < 4; ++r)
                ob[(mt * 16 + 4 * q + r) * Ddim + ncol[nl]] = h[mt][nl][r];
}

extern "C" void kernel_launch(void* const* d_in, const int* in_sizes, int n_in,
                              void* d_out, int out_size, void* d_ws, size_t ws_size,
                              hipStream_t stream) {
    const float* x            = (const float*)d_in[0];
    const float* weight       = (const float*)d_in[1];
    const float* input_weight = (const float*)d_in[2];
    const float* bias         = (const float*)d_in[3];
    const float* tau          = (const float*)d_in[4];
    (void)in_sizes; (void)n_in; (void)out_size; (void)ws_size;

    bf16_t* wsw   = (bf16_t*)d_ws;
    bf16_t* winsw = wsw + 65536;

    static bool attr_set = false;
    if (!attr_set) {
        (void)hipFuncSetAttribute((const void*)rnn_kernel,
                                  hipFuncAttributeMaxDynamicSharedMemorySize,
                                  LDS_TOTAL);
        attr_set = true;
    }

    swz_kernel<<<16, 256, 0, stream>>>(weight, input_weight, wsw, winsw);
    rnn_kernel<<<512, 256, LDS_TOTAL, stream>>>(x, bias, tau,
                                                (const bf16x8*)wsw,
                                                (const bf16x8*)winsw,
                                                (float*)d_out);
}